// Round 14
// baseline (251.426 us; speedup 1.0000x reference)
//
#include <hip/hip_runtime.h>

#define Bb 2
#define Tt 2048
#define Mm 2048
#define Hh 16
#define Dd 128

typedef __attribute__((ext_vector_type(8))) short bf16x8;
typedef __attribute__((ext_vector_type(4))) float f32x4;
typedef __attribute__((ext_vector_type(16))) float f32x16;

__device__ __forceinline__ unsigned short f2bf(float f) {
    unsigned int u = __builtin_bit_cast(unsigned int, f);
    u += 0x7FFFu + ((u >> 16) & 1u);   // RNE
    return (unsigned short)(u >> 16);
}

__device__ __forceinline__ unsigned int cvt_pk_bf16(float lo, float hi) {
    unsigned int r;
    asm("v_cvt_pk_bf16_f32 %0, %1, %2" : "=v"(r) : "v"(lo), "v"(hi));
    return r;
}

__device__ __forceinline__ float fexp2(float x) { return __builtin_amdgcn_exp2f(x); }

__device__ __forceinline__ void gld16(const void* g, void* l) {
    __builtin_amdgcn_global_load_lds(
        (const __attribute__((address_space(1))) void*)g,
        (__attribute__((address_space(3))) void*)l, 16, 0, 0);
}

// ---------------------------------------------------------------- prep kernels

// x (4096 x 2048 fp32) -> xb2 fragment-tiled bf16
__global__ __launch_bounds__(256) void cvt_x2(const float* __restrict__ x,
                                              unsigned short* __restrict__ xb2) {
    const int blk = blockIdx.x;              // 1024 = 32 mt x 32 kt
    const int mt = blk >> 5, kt = blk & 31;
#pragma unroll
    for (int it = 0; it < 4; ++it) {
        int s = it * 256 + threadIdx.x;
        int row = ((s >> 6) & 3) * 32 + (s & 31);
        int k = (s >> 8) * 16 + ((s >> 5) & 1) * 8;
        const float* sp = x + ((long)(mt * 128 + row)) * 2048 + kt * 64 + k;
        float4 a = *(const float4*)sp;
        float4 b = *(const float4*)(sp + 4);
        uint4 pk;
        pk.x = (unsigned int)f2bf(a.x) | ((unsigned int)f2bf(a.y) << 16);
        pk.y = (unsigned int)f2bf(a.z) | ((unsigned int)f2bf(a.w) << 16);
        pk.z = (unsigned int)f2bf(b.x) | ((unsigned int)f2bf(b.y) << 16);
        pk.w = (unsigned int)f2bf(b.z) | ((unsigned int)f2bf(b.w) << 16);
        *(uint4*)(xb2 + (((long)(mt * 32 + kt)) * 1024 + s) * 8) = pk;
    }
}

// qkv weights -> head-major fragment tiles with RoPE column permutation:
// per (hseg = which*16+head, kt): chunk u = kk4*256 + nf*64 + l;
// d = (l&31) + 64*(nf&1) + 32*(nf>>1); k = kk4*16 + (l>>5)*8
__global__ __launch_bounds__(256) void w_qkv_tile(
    const float* __restrict__ wq, const float* __restrict__ wk, const float* __restrict__ wv,
    unsigned short* __restrict__ outBase) {
    __shared__ float tile[64][132];
    const int kt = blockIdx.x;               // 0..31
    const int zy = blockIdx.y;               // 0..47
    const int which = zy >> 4, head = zy & 15;
    const float* src = (which == 0 ? wq : which == 1 ? wk : wv) + (long)head * 2048 * 128;
    const int tid = threadIdx.x;
#pragma unroll
    for (int it = 0; it < 8; ++it) {
        int f = it * 256 + tid;              // 2048 float4s = 64 rows x 32
        int row = f >> 5, c4 = f & 31;
        float4 v = *(const float4*)(src + (long)(kt * 64 + row) * 128 + c4 * 4);
        tile[row][c4 * 4 + 0] = v.x;
        tile[row][c4 * 4 + 1] = v.y;
        tile[row][c4 * 4 + 2] = v.z;
        tile[row][c4 * 4 + 3] = v.w;
    }
    __syncthreads();
    unsigned short* outp = outBase + (((long)(which * 16 + head)) * 32 + kt) * 1024 * 8;
#pragma unroll
    for (int it = 0; it < 4; ++it) {
        int up = it * 256 + tid;
        int kk = up >> 8, nf = (up >> 6) & 3, l = up & 63;
        int il = l & 31, hl = l >> 5;
        int d = il + 64 * (nf & 1) + 32 * (nf >> 1);
        int kl = kk * 16 + hl * 8;
        uint4 pk;
        pk.x = (unsigned int)f2bf(tile[kl + 0][d]) | ((unsigned int)f2bf(tile[kl + 1][d]) << 16);
        pk.y = (unsigned int)f2bf(tile[kl + 2][d]) | ((unsigned int)f2bf(tile[kl + 3][d]) << 16);
        pk.z = (unsigned int)f2bf(tile[kl + 4][d]) | ((unsigned int)f2bf(tile[kl + 5][d]) << 16);
        pk.w = (unsigned int)f2bf(tile[kl + 6][d]) | ((unsigned int)f2bf(tile[kl + 7][d]) << 16);
        *(uint4*)(outp + (long)up * 8) = pk;
    }
}

// plain transpose (for w_ao)
__global__ __launch_bounds__(256) void transpose_cvt(const float* __restrict__ in,
                                                     unsigned short* __restrict__ out,
                                                     int rows, int cols,
                                                     long in_slab, long out_slab) {
    __shared__ float tile[32][33];
    const float* ip = in + (long)blockIdx.z * in_slab;
    unsigned short* op = out + (long)blockIdx.z * out_slab;
    int r0 = blockIdx.x * 32, c0 = blockIdx.y * 32;
    int tx = threadIdx.x & 31, ty = threadIdx.x >> 5;
#pragma unroll
    for (int j = 0; j < 32; j += 8)
        tile[ty + j][tx] = ip[(long)(r0 + ty + j) * cols + c0 + tx];
    __syncthreads();
#pragma unroll
    for (int j = 0; j < 32; j += 8)
        op[(long)(c0 + ty + j) * rows + r0 + tx] = f2bf(tile[tx][ty + j]);
}

__global__ __launch_bounds__(256) void rope_tab(float* __restrict__ cosT,
                                                float* __restrict__ sinT) {
    int idx = blockIdx.x * 256 + threadIdx.x;   // T*64
    int t = idx >> 6, d = idx & 63;
    float freq = powf(10000.f, -(float)d / 64.f);
    float ang = (float)t * freq;
    sinT[idx] = sinf(ang);
    cosT[idx] = cosf(ang);
}

// ---------------------------------------------------------------- QKV projection GEMM v9
// 256x384 block (256-wide + 128-narrow sub-GEMMs), 512 thr (8 waves), 32x32x16.
// Wide: 2M x 4N waves, per-wave 128x64 (16 MFMA / 12 frag-reads per iter).
// BK=32, 3 rotating 32KB fragment-major buffers (96KB LDS, 1 block/CU, grid=256
// exact fill), R13 protocol: stage t+2 -> counted vmcnt + lgkm0 -> ONE barrier
// -> reg-prefetch t+1 frags -> MFMA cluster (reads hide under MFMAs).
template <bool WIDE>
__device__ __forceinline__ void proj_sub9(
    const unsigned short* __restrict__ xb2,
    const unsigned short* __restrict__ wT2,
    char* lds, int bm, int offc,
    unsigned short* __restrict__ qO, unsigned short* __restrict__ kO,
    unsigned short* __restrict__ vtO,
    const float* __restrict__ cosT, const float* __restrict__ sinT, int tid) {
    const int lane = tid & 63, wave = tid >> 6;
    const int il = lane & 31, hl = lane >> 5;
    const int wm = WIDE ? (wave >> 2) : (wave >> 1);
    const int wn = WIDE ? (wave & 3) : (wave & 1);
    const int hseg0 = offc >> 7;
    const int mode = offc >> 11;
    constexpr int MF = WIDE ? 4 : 2;
    constexpr int NFR = WIDE ? 12 : 8;   // frags per iter (per wave)
    constexpr int FS = WIDE ? 6 : 4;     // frags per kk2

    f32x16 acc[MF][2];
#pragma unroll
    for (int a = 0; a < MF; ++a)
#pragma unroll
        for (int b2 = 0; b2 < 2; ++b2)
#pragma unroll
            for (int e = 0; e < 16; ++e) acc[a][b2][e] = 0.f;

    // stage K-half kt2 (32 k) into buffer at bufOff: A 1024 chunks, B 1024(wide)/512(narrow)
    auto stageTo = [&](int bufOff, int kt2) {
        const int kt = kt2 >> 1, hf = kt2 & 1;
        char* dst = lds + bufOff;
#pragma unroll
        for (int i = 0; i < 2; ++i) {
            int f = i * 512 + tid;
            int kk = f >> 9, rf = (f >> 6) & 7, l = f & 63;
            int mt = 2 * bm + (rf >> 2), rb = rf & 3;
            gld16(xb2 + (((long)(mt * 32 + kt)) * 1024 + (2 * hf + kk) * 256 + rb * 64 + l) * 8,
                  dst + f * 16);
        }
        if (WIDE) {
#pragma unroll
            for (int i = 0; i < 2; ++i) {
                int g = i * 512 + tid;
                int kk = g >> 9, cf = (g >> 6) & 7, l = g & 63;
                int hs = hseg0 + (cf >> 2), nf = cf & 3;
                gld16(wT2 + (((long)(hs * 32 + kt)) * 1024 + (2 * hf + kk) * 256 + nf * 64 + l) * 8,
                      dst + 16384 + g * 16);
            }
        } else {
            int g = tid;
            int kk = g >> 8, nf = (g >> 6) & 3, l = g & 63;
            gld16(wT2 + (((long)(hseg0 * 32 + kt)) * 1024 + (2 * hf + kk) * 256 + nf * 64 + l) * 8,
                  dst + 16384 + g * 16);
        }
    };

    // read this wave's NFR fragments of buffer bufOff into regs (lane-linear, 0-conflict)
    auto prefetch = [&](bf16x8 (&fr)[NFR], int bufOff) {
        const char* bc = lds + bufOff;
#pragma unroll
        for (int kk2 = 0; kk2 < 2; ++kk2) {
#pragma unroll
            for (int mf = 0; mf < MF; ++mf)
                fr[kk2 * FS + mf] = *(const bf16x8*)(bc + (kk2 * 512 + (wm * MF + mf) * 64 + lane) * 16);
#pragma unroll
            for (int nf = 0; nf < 2; ++nf)
                fr[kk2 * FS + MF + nf] = *(const bf16x8*)(bc + 16384 +
                    ((WIDE ? kk2 * 512 : kk2 * 256) + (wn * 2 + nf) * 64 + lane) * 16);
        }
    };

    auto domfma = [&](bf16x8 (&fr)[NFR]) {
        __builtin_amdgcn_s_setprio(1);
#pragma unroll
        for (int kk2 = 0; kk2 < 2; ++kk2)
#pragma unroll
            for (int mf = 0; mf < MF; ++mf)
#pragma unroll
                for (int nf = 0; nf < 2; ++nf)
                    acc[mf][nf] = __builtin_amdgcn_mfma_f32_32x32x16_bf16(
                        fr[kk2 * FS + mf], fr[kk2 * FS + MF + nf], acc[mf][nf], 0, 0, 0);
        __builtin_amdgcn_s_setprio(0);
    };

    bf16x8 fA[NFR], fB[NFR];

    stageTo(0, 0);
    stageTo(32768, 1);
    if (WIDE) asm volatile("s_waitcnt vmcnt(4)" ::: "memory");
    else      asm volatile("s_waitcnt vmcnt(3)" ::: "memory");
    __builtin_amdgcn_s_barrier();
    prefetch(fA, 0);

    int curOff = 0;
    for (int p = 0; p < 31; ++p) {
        {   // t = 2p (frags fA)
            int preOff = curOff + 65536; if (preOff >= 98304) preOff -= 98304;
            stageTo(preOff, 2 * p + 2);
            if (WIDE) asm volatile("s_waitcnt vmcnt(4) lgkmcnt(0)" ::: "memory");
            else      asm volatile("s_waitcnt vmcnt(3) lgkmcnt(0)" ::: "memory");
            __builtin_amdgcn_s_barrier();
            int nxtOff = curOff + 32768; if (nxtOff >= 98304) nxtOff -= 98304;
            prefetch(fB, nxtOff);
            domfma(fA);
            curOff = nxtOff;
        }
        {   // t = 2p+1 (frags fB)
            int preOff = curOff + 65536; if (preOff >= 98304) preOff -= 98304;
            stageTo(preOff, 2 * p + 3);
            if (WIDE) asm volatile("s_waitcnt vmcnt(4) lgkmcnt(0)" ::: "memory");
            else      asm volatile("s_waitcnt vmcnt(3) lgkmcnt(0)" ::: "memory");
            __builtin_amdgcn_s_barrier();
            int nxtOff = curOff + 32768; if (nxtOff >= 98304) nxtOff -= 98304;
            prefetch(fA, nxtOff);
            domfma(fB);
            curOff = nxtOff;
        }
    }
    // t = 62: stage 63 still in flight -> drain, then pipeline tail
    asm volatile("s_waitcnt vmcnt(0) lgkmcnt(0)" ::: "memory");
    __builtin_amdgcn_s_barrier();
    {
        int nxtOff = curOff + 32768; if (nxtOff >= 98304) nxtOff -= 98304;
        prefetch(fB, nxtOff);
        domfma(fA);
    }
    domfma(fB);   // t = 63

    const int b = bm >> 3;
    const int t0 = (bm & 7) * 256;
    const int head_g = WIDE ? (hseg0 + (wn >> 1)) : hseg0;
    const int head_l = head_g & 15;
    const int opar = WIDE ? (wn & 1) : wn;       // which ord-pair the wave holds
    constexpr int WMS = WIDE ? 128 : 64;         // wave M-stride

    if (mode < 2) {
        const float qs = (mode == 0) ? 0.011271055f : 1.0f;  // log2(e)/D folded into q
        unsigned short* outp = (mode == 0) ? qO : kO;
        long hb = ((long)(b * Hh + head_l)) * Tt;
        int d_lo = il + 32 * opar;
#pragma unroll
        for (int mf = 0; mf < MF; ++mf)
#pragma unroll
            for (int reg = 0; reg < 16; ++reg) {
                int r = (reg & 3) + 8 * (reg >> 2) + 4 * hl;
                int tt = t0 + wm * WMS + mf * 32 + r;
                float c = cosT[tt * 64 + d_lo], s = sinT[tt * 64 + d_lo];
                float ev = acc[mf][0][reg], od = acc[mf][1][reg];
                long base = (hb + tt) * Dd;
                outp[base + d_lo]      = f2bf((ev * c - od * s) * qs);
                outp[base + d_lo + 64] = f2bf((ev * s + od * c) * qs);
            }
    } else {
        // V transposed out: per-wave 4KB patch per mf (64 dslot x 32 t)
        __syncthreads();   // all waves done with LDS buffers before patch reuse
        char* patch = lds + wave * 4096;
        long hdbase = ((long)(b * Hh + head_l)) * Dd * Tt;
#pragma unroll
        for (int mf = 0; mf < MF; ++mf) {
#pragma unroll
            for (int nf = 0; nf < 2; ++nf) {
                int dslot = nf * 32 + il;
                int swz = (dslot & 3) << 4;
#pragma unroll
                for (int qg = 0; qg < 4; ++qg) {
                    uint2 w;
                    w.x = cvt_pk_bf16(acc[mf][nf][qg * 4 + 0], acc[mf][nf][qg * 4 + 1]);
                    w.y = cvt_pk_bf16(acc[mf][nf][qg * 4 + 2], acc[mf][nf][qg * 4 + 3]);
                    *(uint2*)(patch + dslot * 64 + ((qg * 16 + hl * 8) ^ swz)) = w;
                }
            }
            __builtin_amdgcn_s_waitcnt(0);
#pragma unroll
            for (int p2 = 0; p2 < 4; ++p2) {
                int dslot = p2 * 16 + (lane >> 2);
                int t8 = lane & 3;
                uint4 v = *(const uint4*)(patch + dslot * 64 + ((t8 * 16) ^ ((dslot & 3) << 4)));
                int o = opar * 2 + (dslot >> 5), il2 = dslot & 31;
                int dd = il2 + 32 * (o >> 1) + 64 * (o & 1);
                int tg = t0 + wm * WMS + mf * 32 + t8 * 8;
                *(uint4*)(vtO + hdbase + (long)dd * Tt + tg) = v;
            }
            __builtin_amdgcn_s_waitcnt(0);
        }
    }
}

__global__ __launch_bounds__(512, 2) void proj_gemm9(
    const unsigned short* __restrict__ xb2,
    const unsigned short* __restrict__ wT2,
    unsigned short* __restrict__ qO,
    unsigned short* __restrict__ kO,
    unsigned short* __restrict__ vtO,
    const float* __restrict__ cosT,
    const float* __restrict__ sinT) {
    __shared__ __align__(16) char lds[98304];
    const int bm = blockIdx.x;          // 0..15 (256 rows each)
    const int bc = blockIdx.y;          // 0..15
    const int s = bc * 384;
    const bool swap = ((s & 2047) == 1920);
    const int offw = swap ? s + 128 : s;
    const int offn = swap ? s : s + 256;
    const int tid = threadIdx.x;

    proj_sub9<true>(xb2, wT2, lds, bm, offw, qO, kO, vtO, cosT, sinT, tid);
    __syncthreads();
    proj_sub9<false>(xb2, wT2, lds, bm, offn, qO, kO, vtO, cosT, sinT, tid);
}

// ---------------------------------------------------------------- flash attention (swapped QK^T, 32x32x16)
__global__ __launch_bounds__(256) void attn_kernel(
    const unsigned short* __restrict__ q,
    const unsigned short* __restrict__ k,
    const unsigned short* __restrict__ vt,
    unsigned short* __restrict__ o) {
    __shared__ __align__(16) unsigned short lds[32768];

    const int lid = (int)blockIdx.x;
    const int p = lid & 255;
    const int bh = p & 31;
    const int q0 = p >> 5;
    const int qb = (lid >> 8) ? (15 - q0) : q0;

    const int tid = threadIdx.x, lane = tid & 63, wave = tid >> 6;
    const int h = lane >> 5, iln = lane & 31;

    const unsigned short* qp = q + (long)bh * Tt * Dd;
    const unsigned short* kp = k + (long)bh * Tt * Dd;
    const unsigned short* vp = vt + (long)bh * Dd * Tt;

    const int i_g = qb * 128 + wave * 32 + iln;
    bf16x8 qf[8];
#pragma unroll
    for (int kk = 0; kk < 8; ++kk)
        qf[kk] = *(const bf16x8*)(qp + (long)i_g * Dd + kk * 16 + h * 8);

    f32x16 accO[4];
#pragma unroll
    for (int nb = 0; nb < 4; ++nb)
#pragma unroll
        for (int e = 0; e < 16; ++e) accO[nb][e] = 0.f;

    float m_r = -1e30f, l_r = 0.f;
    const int ntiles = 2 * qb + 2;

    auto stage = [&](int buf, int tix) {
        const int j0s = tix * 64;
#pragma unroll
        for (int it = 0; it < 4; ++it) {
            int f = it * 256 + tid;
            int rk = f >> 4, ck = f & 15;
            gld16(kp + ((long)(j0s + rk) * Dd + ((ck ^ (rk & 7)) << 3)),
                  (char*)lds + buf * 16384 + f * 16);
            int rv = f >> 3, cv = f & 7;
            gld16(vp + ((long)rv * Tt + j0s + ((cv ^ (rv & 7)) << 3)),
                  (char*)lds + 32768 + buf * 16384 + f * 16);
        }
    };

    stage(0, 0);

    for (int tix = 0; tix < ntiles; ++tix) {
        const int cur = tix & 1;
        const int j0 = tix * 64;
        if (tix + 1 < ntiles) {
            stage(cur ^ 1, tix + 1);
            asm volatile("s_waitcnt vmcnt(8)" ::: "memory");
        } else {
            asm volatile("s_waitcnt vmcnt(0)" ::: "memory");
        }
        __builtin_amdgcn_s_barrier();

        const char* Kb = (const char*)lds + cur * 16384;
        const char* Vb = (const char*)lds + 32768 + cur * 16384;

        f32x16 sacc[2];
#pragma unroll
        for (int mb = 0; mb < 2; ++mb)
#pragma unroll
            for (int e = 0; e < 16; ++e) sacc[mb][e] = 0.f;

        __builtin_amdgcn_s_setprio(1);
#pragma unroll
        for (int mb = 0; mb < 2; ++mb) {
            int row = mb * 32 + iln;
            const char* Kr = Kb + row * 256;
            int sw = row & 7;
#pragma unroll
            for (int kk = 0; kk < 8; ++kk) {
                bf16x8 kf = *(const bf16x8*)(Kr + 16 * ((kk * 2 + h) ^ sw));
                sacc[mb] = __builtin_amdgcn_mfma_f32_32x32x16_bf16(kf, qf[kk], sacc[mb], 0, 0, 0);
            }
        }
        __builtin_amdgcn_s_setprio(0);

        const bool domask = (j0 + 63 > qb * 128);
        if (domask) {
#pragma unroll
            for (int mb = 0; mb < 2; ++mb)
#pragma unroll
                for (int reg = 0; reg < 16; ++reg) {
                    int j = j0 + mb * 32 + (reg & 3) + 8 * (reg >> 2) + 4 * h;
                    if (j > i_g) sacc[mb][reg] = -1e30f;
                }
        }

        float red[16];
#pragma unroll
        for (int r = 0; r < 16; ++r) red[r] = fmaxf(sacc[0][r], sacc[1][r]);
#pragma unroll
        for (int s = 8; s >= 1; s >>= 1)
#pragma unroll
            for (int r = 0; r < s; ++r) red[r] = fmaxf(red[r], red[r + s]);
        float mx = fmaxf(red[0], __shfl_xor(red[0], 32, 64));

        if (__any(mx > m_r + 8.f)) {
            float mn = fmaxf(m_r, mx);
            float corr = fexp2(m_r - mn);
            m_r = mn;
            l_r *= corr;
#pragma unroll
            for (int reg = 0; reg < 16; ++reg) {
                int rrow = (reg & 3) + 8 * (reg >> 2) + 4 * h;
                float c = __shfl(corr, rrow, 64);
#pragma unroll
                for (int nb = 0; nb < 4; ++nb) accO[nb][reg] *= c;
            }
        }

        float pe[2][16];
#pragma unroll
        for (int mb = 0; mb < 2; ++mb)
#pragma unroll
            for (int r = 0; r < 16; ++r) pe[mb][r] = fexp2(sacc[mb][r] - m_r);
        float sr[16];
#pragma unroll
        for (int r = 0; r < 16; ++r) sr[r] = pe[0][r] + pe[1][r];
#pragma unroll
        for (int s = 8; s >= 1; s >>= 1)
#pragma unroll
            for (int r = 0; r < s; ++r) sr[r] += sr[r + s];
        l_r += sr[0] + __shfl_xor(sr[0], 32, 64);

        unsigned int pu[2][8];
#pragma unroll
        for (int mb = 0; mb < 2; ++mb)
#pragma unroll
            for (int t = 0; t < 8; ++t)
                pu[mb][t] = cvt_pk_bf16(pe[mb][2 * t], pe[mb][2 * t + 1]);

        unsigned int rv2[2][4];
#pragma unroll
        for (int mb = 0; mb < 2; ++mb)
#pragma unroll
            for (int u = 0; u < 4; ++u) {
                unsigned int sv = h ? pu[mb][(u & 1) + 4 * (u >> 1)]
                                    : pu[mb][2 + (u & 1) + 4 * (u >> 1)];
                rv2[mb][u] = __shfl_xor(sv, 32, 64);
            }

        __builtin_amdgcn_s_setprio(1);
#pragma unroll
        for (int kk2 = 0; kk2 < 4; ++kk2) {
            const int mb = kk2 >> 1, c2 = kk2 & 1;
            unsigned int w0 = h ? rv2[mb][2 * c2 + 0] : pu[mb][4 * c2 + 0];
            unsigned int w1 = h ? rv2[mb][2 * c2 + 1] : pu[mb][4 * c2 + 1];
            unsigned int w2 = h ? pu[mb][4 * c2 + 2] : rv2[mb][2 * c2 + 0];
            unsigned int w3 = h ? pu[mb][4 * c2 + 3] : rv2[mb][2 * c2 + 1];
            uint4 aw; aw.x = w0; aw.y = w1; aw.z = w2; aw.w = w3;
            bf16x8 af = __builtin_bit_cast(bf16x8, aw);
#pragma unroll
            for (int nb = 0; nb < 4; ++nb) {
                int dd = nb * 32 + iln;
                int byte = dd * 128 + 16 * ((kk2 * 2 + h) ^ (dd & 7));
                bf16x8 vf = *(const bf16x8*)(Vb + byte);
                accO[nb] = __builtin_amdgcn_mfma_f32_32x32x16_bf16(af, vf, accO[nb], 0, 0, 0);
            }
        }
        __builtin_amdgcn_s_setprio(0);

        asm volatile("" ::: "memory");
        __builtin_amdgcn_s_barrier();
    }

    const int b = bh >> 4, hh = bh & 15;
    float invl = 1.f / l_r;
#pragma unroll
    for (int reg = 0; reg < 16; ++reg) {
        int rrow = (reg & 3) + 8 * (reg >> 2) + 4 * h;
        float iv = __shfl(invl, rrow, 64);
        int t = qb * 128 + wave * 32 + rrow;
        long base = ((long)(b * Tt + t) * Hh + hh) * Dd;
#pragma unroll
        for (int nb = 0; nb < 4; ++nb)
            o[base + nb * 32 + iln] = f2bf(accO[nb][reg] * iv);
    }
}

// ---------------------------------------------------------------- output projection GEMM
__global__ __launch_bounds__(256) void out_gemm(
    const unsigned short* __restrict__ oIn,
    const unsigned short* __restrict__ woT,
    float* __restrict__ out) {
    __shared__ __align__(16) unsigned short smem[32768];
    const int bm = blockIdx.x, bn = blockIdx.y;
    const int tid = threadIdx.x;
    const int lane = tid & 63;
    const int wave = tid >> 6;
    const int g = lane >> 4;
    const int ln = lane & 15;

    const unsigned short* arow = oIn + (long)bm * 128 * Mm;
    const unsigned short* brow = woT + (long)bn * 128 * Mm;

    f32x4 acc[2][8];
#pragma unroll
    for (int a = 0; a < 2; ++a)
#pragma unroll
        for (int b2 = 0; b2 < 8; ++b2)
#pragma unroll
            for (int e = 0; e < 4; ++e) acc[a][b2][e] = 0.f;

    auto stage = [&](int buf, int kt) {
        const int k0 = kt * 64;
#pragma unroll
        for (int it = 0; it < 4; ++it) {
            int f = it * 256 + tid;
            int r = f >> 3, c = f & 7;
            long off = (long)r * Mm + k0 + ((c ^ (r & 7)) << 3);
            gld16(arow + off, (char*)smem + buf * 32768 + f * 16);
            gld16(brow + off, (char*)smem + buf * 32768 + 16384 + f * 16);
        }
    };

    stage(0, 0);

    for (int kt = 0; kt < Mm / 64; ++kt) {
        const int cur = kt & 1;
        asm volatile("s_waitcnt vmcnt(0)" ::: "memory");   // stage(kt) landed
        __builtin_amdgcn_s_barrier();
        if (kt + 1 < Mm / 64) stage(cur ^ 1, kt + 1);

        const char* Ab = (const char*)smem + cur * 32768;
        const char* Bv = Ab + 16384;
#pragma unroll
        for (int kc = 0; kc < 2; ++kc) {
            bf16x8 af[2];
#pragma unroll
            for (int rf = 0; rf < 2; ++rf) {
                int row = wave * 32 + rf * 16 + ln;
                int byte = (row * 128 + kc * 64 + g * 16) ^ ((row & 7) << 4);
                af[rf] = *(const bf16x8*)(Ab + byte);
            }
#pragma unroll
            for (int ni = 0; ni < 8; ++ni) {
                int row = ni * 16 + ln;
                int byte = (row * 128 + kc * 64 + g * 16) ^ ((row & 7) << 4);
                bf16x8 bfv = *(const bf16x8*)(Bv + byte);
#pragma unroll
                for (int rf = 0; rf < 2; ++rf)
                    acc[rf][ni] = __builtin_amdgcn_mfma_f32_16x16x32_bf16(af[rf], bfv, acc[rf][ni], 0, 0, 0);
            }
        }
        asm volatile("" ::: "memory");
    }

#pragma unroll
    for (int rf = 0; rf < 2; ++rf)
#pragma unroll
        for (int reg = 0; reg < 4; ++reg) {
            long row = bm * 128 + wave * 32 + rf * 16 + g * 4 + reg;
#pragma unroll
            for (int ni = 0; ni < 8; ++ni)
                out[row * Mm + bn * 128 + ni * 16 + ln] = acc[rf][ni][reg];
        }
}

// ---------------------------------------------------------------- launch

extern "C" void kernel_launch(void* const* d_in, const int* in_sizes, int n_in,
                              void* d_out, int out_size, void* d_ws, size_t ws_size,
                              hipStream_t stream) {
    const float* x    = (const float*)d_in[0];
    const float* w_aq = (const float*)d_in[1];
    const float* w_ak = (const float*)d_in[2];
    const float* w_av = (const float*)d_in[3];
    const float* w_ao = (const float*)d_in[4];
    float* out = (float*)d_out;

    char* ws = (char*)d_ws;
    const long SZ_BTM = 16777216;   // B*T*M * 2B
    const long SZ_W   = 8388608;    // 2048*2048 * 2B
    unsigned short* xb2 = (unsigned short*)(ws);
    unsigned short* qB  = (unsigned short*)(ws + SZ_BTM);
    unsigned short* kB  = (unsigned short*)(ws + 2 * SZ_BTM);
    unsigned short* vtB = (unsigned short*)(ws + 3 * SZ_BTM);
    unsigned short* oB  = (unsigned short*)(ws + 4 * SZ_BTM);
    unsigned short* wT2 = (unsigned short*)(ws + 5 * SZ_BTM);             // 24MB tiled qkv
    unsigned short* woT = (unsigned short*)(ws + 5 * SZ_BTM + 3 * SZ_W);
    float* cosT = (float*)(ws + 5 * SZ_BTM + 4 * SZ_W);
    float* sinT = (float*)(ws + 5 * SZ_BTM + 4 * SZ_W + 524288);

    cvt_x2<<<1024, 256, 0, stream>>>(x, xb2);
    w_qkv_tile<<<dim3(32, 48), 256, 0, stream>>>(w_aq, w_ak, w_av, wT2);
    transpose_cvt<<<dim3(64, 64, 1), 256, 0, stream>>>(w_ao, woT, 2048, 2048, 0, 0);
    rope_tab<<<512, 256, 0, stream>>>(cosT, sinT);

    proj_gemm9<<<dim3(16, 16), 512, 0, stream>>>(xb2, wT2, qB, kB, vtB, cosT, sinT);
    attn_kernel<<<dim3(512), 256, 0, stream>>>(qB, kB, vtB, oB);
    out_gemm<<<dim3(32, 16), 256, 0, stream>>>(oB, woT, out);
}

// Round 15
// 242.052 us; speedup vs baseline: 1.0387x; 1.0387x over previous
//
#include <hip/hip_runtime.h>

#define Bb 2
#define Tt 2048
#define Mm 2048
#define Hh 16
#define Dd 128

typedef __attribute__((ext_vector_type(8))) short bf16x8;
typedef __attribute__((ext_vector_type(4))) float f32x4;
typedef __attribute__((ext_vector_type(16))) float f32x16;

__device__ __forceinline__ unsigned short f2bf(float f) {
    unsigned int u = __builtin_bit_cast(unsigned int, f);
    u += 0x7FFFu + ((u >> 16) & 1u);   // RNE
    return (unsigned short)(u >> 16);
}

__device__ __forceinline__ unsigned int cvt_pk_bf16(float lo, float hi) {
    unsigned int r;
    asm("v_cvt_pk_bf16_f32 %0, %1, %2" : "=v"(r) : "v"(lo), "v"(hi));
    return r;
}

__device__ __forceinline__ float fexp2(float x) { return __builtin_amdgcn_exp2f(x); }

__device__ __forceinline__ void gld16(const void* g, void* l) {
    __builtin_amdgcn_global_load_lds(
        (const __attribute__((address_space(1))) void*)g,
        (__attribute__((address_space(3))) void*)l, 16, 0, 0);
}

// ---------------------------------------------------------------- prep kernels

// x (4096 x 2048 fp32) -> xb2 fragment-tiled bf16
__global__ __launch_bounds__(256) void cvt_x2(const float* __restrict__ x,
                                              unsigned short* __restrict__ xb2) {
    const int blk = blockIdx.x;              // 1024 = 32 mt x 32 kt
    const int mt = blk >> 5, kt = blk & 31;
#pragma unroll
    for (int it = 0; it < 4; ++it) {
        int s = it * 256 + threadIdx.x;
        int row = ((s >> 6) & 3) * 32 + (s & 31);
        int k = (s >> 8) * 16 + ((s >> 5) & 1) * 8;
        const float* sp = x + ((long)(mt * 128 + row)) * 2048 + kt * 64 + k;
        float4 a = *(const float4*)sp;
        float4 b = *(const float4*)(sp + 4);
        uint4 pk;
        pk.x = (unsigned int)f2bf(a.x) | ((unsigned int)f2bf(a.y) << 16);
        pk.y = (unsigned int)f2bf(a.z) | ((unsigned int)f2bf(a.w) << 16);
        pk.z = (unsigned int)f2bf(b.x) | ((unsigned int)f2bf(b.y) << 16);
        pk.w = (unsigned int)f2bf(b.z) | ((unsigned int)f2bf(b.w) << 16);
        *(uint4*)(xb2 + (((long)(mt * 32 + kt)) * 1024 + s) * 8) = pk;
    }
}

// qkv weights -> head-major fragment tiles with RoPE column permutation
__global__ __launch_bounds__(256) void w_qkv_tile(
    const float* __restrict__ wq, const float* __restrict__ wk, const float* __restrict__ wv,
    unsigned short* __restrict__ outBase) {
    __shared__ float tile[64][132];
    const int kt = blockIdx.x;               // 0..31
    const int zy = blockIdx.y;               // 0..47
    const int which = zy >> 4, head = zy & 15;
    const float* src = (which == 0 ? wq : which == 1 ? wk : wv) + (long)head * 2048 * 128;
    const int tid = threadIdx.x;
#pragma unroll
    for (int it = 0; it < 8; ++it) {
        int f = it * 256 + tid;              // 2048 float4s = 64 rows x 32
        int row = f >> 5, c4 = f & 31;
        float4 v = *(const float4*)(src + (long)(kt * 64 + row) * 128 + c4 * 4);
        tile[row][c4 * 4 + 0] = v.x;
        tile[row][c4 * 4 + 1] = v.y;
        tile[row][c4 * 4 + 2] = v.z;
        tile[row][c4 * 4 + 3] = v.w;
    }
    __syncthreads();
    unsigned short* outp = outBase + (((long)(which * 16 + head)) * 32 + kt) * 1024 * 8;
#pragma unroll
    for (int it = 0; it < 4; ++it) {
        int up = it * 256 + tid;
        int kk = up >> 8, nf = (up >> 6) & 3, l = up & 63;
        int il = l & 31, hl = l >> 5;
        int d = il + 64 * (nf & 1) + 32 * (nf >> 1);
        int kl = kk * 16 + hl * 8;
        uint4 pk;
        pk.x = (unsigned int)f2bf(tile[kl + 0][d]) | ((unsigned int)f2bf(tile[kl + 1][d]) << 16);
        pk.y = (unsigned int)f2bf(tile[kl + 2][d]) | ((unsigned int)f2bf(tile[kl + 3][d]) << 16);
        pk.z = (unsigned int)f2bf(tile[kl + 4][d]) | ((unsigned int)f2bf(tile[kl + 5][d]) << 16);
        pk.w = (unsigned int)f2bf(tile[kl + 6][d]) | ((unsigned int)f2bf(tile[kl + 7][d]) << 16);
        *(uint4*)(outp + (long)up * 8) = pk;
    }
}

// plain transpose (for w_ao)
__global__ __launch_bounds__(256) void transpose_cvt(const float* __restrict__ in,
                                                     unsigned short* __restrict__ out,
                                                     int rows, int cols,
                                                     long in_slab, long out_slab) {
    __shared__ float tile[32][33];
    const float* ip = in + (long)blockIdx.z * in_slab;
    unsigned short* op = out + (long)blockIdx.z * out_slab;
    int r0 = blockIdx.x * 32, c0 = blockIdx.y * 32;
    int tx = threadIdx.x & 31, ty = threadIdx.x >> 5;
#pragma unroll
    for (int j = 0; j < 32; j += 8)
        tile[ty + j][tx] = ip[(long)(r0 + ty + j) * cols + c0 + tx];
    __syncthreads();
#pragma unroll
    for (int j = 0; j < 32; j += 8)
        op[(long)(c0 + ty + j) * rows + r0 + tx] = f2bf(tile[tx][ty + j]);
}

__global__ __launch_bounds__(256) void rope_tab(float* __restrict__ cosT,
                                                float* __restrict__ sinT) {
    int idx = blockIdx.x * 256 + threadIdx.x;   // T*64
    int t = idx >> 6, d = idx & 63;
    float freq = powf(10000.f, -(float)d / 64.f);
    float ang = (float)t * freq;
    sinT[idx] = sinf(ang);
    cosT[idx] = cosf(ang);
}

// ---------------------------------------------------------------- QKV projection GEMM v10
// 256x384 block (256-wide + 128-narrow), 512 thr (8 waves), 32x32x16, BK=64,
// DOUBLE-buffered 2x64KB fragment-major LDS (128KB, 1 blk/CU), counted vmcnt,
// 32 iters/sub-GEMM (half of R14): fixed per-iter overheads amortized 2x.
// Reads+MFMAs compiler-scheduled (fine lgkmcnt interleave).
template <bool WIDE>
__device__ __forceinline__ void proj_sub10(
    const unsigned short* __restrict__ xb2,
    const unsigned short* __restrict__ wT2,
    char* lds, int bm, int offc,
    unsigned short* __restrict__ qO, unsigned short* __restrict__ kO,
    unsigned short* __restrict__ vtO,
    const float* __restrict__ cosT, const float* __restrict__ sinT, int tid) {
    const int lane = tid & 63, wave = tid >> 6;
    const int il = lane & 31, hl = lane >> 5;
    const int wm = WIDE ? (wave >> 2) : (wave >> 1);
    const int wn = WIDE ? (wave & 3) : (wave & 1);
    const int hseg0 = offc >> 7;
    const int mode = offc >> 11;
    constexpr int MF = WIDE ? 4 : 2;

    f32x16 acc[MF][2];
#pragma unroll
    for (int a = 0; a < MF; ++a)
#pragma unroll
        for (int b2 = 0; b2 < 2; ++b2)
#pragma unroll
            for (int e = 0; e < 16; ++e) acc[a][b2][e] = 0.f;

    // stage full K-tile kt (64 k) into buffer: A 2048 chunks, B 2048(wide)/1024(narrow)
    auto stageTo = [&](int buf, int kt) {
        char* dst = lds + buf * 65536;
#pragma unroll
        for (int i = 0; i < 4; ++i) {
            int f = i * 512 + tid;
            int sub = f >> 10, s = f & 1023;
            gld16(xb2 + (((long)((2 * bm + sub) * 32 + kt)) * 1024 + s) * 8, dst + f * 16);
        }
        if (WIDE) {
#pragma unroll
            for (int i = 0; i < 4; ++i) {
                int g = i * 512 + tid;
                int hs = g >> 10, u = g & 1023;
                gld16(wT2 + (((long)((hseg0 + hs) * 32 + kt)) * 1024 + u) * 8,
                      dst + 32768 + g * 16);
            }
        } else {
#pragma unroll
            for (int i = 0; i < 2; ++i) {
                int g = i * 512 + tid;
                gld16(wT2 + (((long)(hseg0 * 32 + kt)) * 1024 + g) * 8,
                      dst + 32768 + g * 16);
            }
        }
    };

    stageTo(0, 0);

    for (int t = 0; t < 32; ++t) {
        const int cur = t & 1;
        if (t + 1 < 32) {
            stageTo(cur ^ 1, t + 1);
            if (WIDE) asm volatile("s_waitcnt vmcnt(8)" ::: "memory");
            else      asm volatile("s_waitcnt vmcnt(6)" ::: "memory");
        } else {
            asm volatile("s_waitcnt vmcnt(0)" ::: "memory");
        }
        __builtin_amdgcn_s_barrier();

        const char* bc = lds + cur * 65536;
        __builtin_amdgcn_s_setprio(1);
#pragma unroll
        for (int kk = 0; kk < 4; ++kk) {
            bf16x8 af[MF], bf[2];
#pragma unroll
            for (int mf = 0; mf < MF; ++mf) {
                int chunk = WIDE ? (wm * 1024 + kk * 256 + mf * 64 + lane)
                                 : ((wm >> 1) * 1024 + kk * 256 + ((wm & 1) * 2 + mf) * 64 + lane);
                af[mf] = *(const bf16x8*)(bc + chunk * 16);
            }
#pragma unroll
            for (int nf2 = 0; nf2 < 2; ++nf2) {
                int chunk = WIDE ? ((wn >> 1) * 1024 + kk * 256 + ((wn & 1) * 2 + nf2) * 64 + lane)
                                 : (kk * 256 + (wn * 2 + nf2) * 64 + lane);
                bf[nf2] = *(const bf16x8*)(bc + 32768 + chunk * 16);
            }
#pragma unroll
            for (int mf = 0; mf < MF; ++mf)
#pragma unroll
                for (int nf2 = 0; nf2 < 2; ++nf2)
                    acc[mf][nf2] = __builtin_amdgcn_mfma_f32_32x32x16_bf16(
                        af[mf], bf[nf2], acc[mf][nf2], 0, 0, 0);
        }
        __builtin_amdgcn_s_setprio(0);
        asm volatile("" ::: "memory");
        __builtin_amdgcn_s_barrier();
    }

    const int b = bm >> 3;
    const int t0 = (bm & 7) * 256;
    const int head_g = WIDE ? (hseg0 + (wn >> 1)) : hseg0;
    const int head_l = head_g & 15;
    const int opar = WIDE ? (wn & 1) : wn;       // which ord-pair the wave holds
    constexpr int WMS = WIDE ? 128 : 64;         // wave M-stride

    if (mode < 2) {
        const float qs = (mode == 0) ? 0.011271055f : 1.0f;  // log2(e)/D folded into q
        unsigned short* outp = (mode == 0) ? qO : kO;
        long hb = ((long)(b * Hh + head_l)) * Tt;
        int d_lo = il + 32 * opar;
#pragma unroll
        for (int mf = 0; mf < MF; ++mf)
#pragma unroll
            for (int reg = 0; reg < 16; ++reg) {
                int r = (reg & 3) + 8 * (reg >> 2) + 4 * hl;
                int tt = t0 + wm * WMS + mf * 32 + r;
                float c = cosT[tt * 64 + d_lo], s = sinT[tt * 64 + d_lo];
                float ev = acc[mf][0][reg], od = acc[mf][1][reg];
                long base = (hb + tt) * Dd;
                outp[base + d_lo]      = f2bf((ev * c - od * s) * qs);
                outp[base + d_lo + 64] = f2bf((ev * s + od * c) * qs);
            }
    } else {
        // V transposed out: per-wave 4KB patch per mf (64 dslot x 32 t)
        __syncthreads();   // all waves done with LDS buffers before patch reuse
        char* patch = lds + wave * 4096;
        long hdbase = ((long)(b * Hh + head_l)) * Dd * Tt;
#pragma unroll
        for (int mf = 0; mf < MF; ++mf) {
#pragma unroll
            for (int nf = 0; nf < 2; ++nf) {
                int dslot = nf * 32 + il;
                int swz = (dslot & 3) << 4;
#pragma unroll
                for (int qg = 0; qg < 4; ++qg) {
                    uint2 w;
                    w.x = cvt_pk_bf16(acc[mf][nf][qg * 4 + 0], acc[mf][nf][qg * 4 + 1]);
                    w.y = cvt_pk_bf16(acc[mf][nf][qg * 4 + 2], acc[mf][nf][qg * 4 + 3]);
                    *(uint2*)(patch + dslot * 64 + ((qg * 16 + hl * 8) ^ swz)) = w;
                }
            }
            __builtin_amdgcn_s_waitcnt(0);
#pragma unroll
            for (int p2 = 0; p2 < 4; ++p2) {
                int dslot = p2 * 16 + (lane >> 2);
                int t8 = lane & 3;
                uint4 v = *(const uint4*)(patch + dslot * 64 + ((t8 * 16) ^ ((dslot & 3) << 4)));
                int o = opar * 2 + (dslot >> 5), il2 = dslot & 31;
                int dd = il2 + 32 * (o >> 1) + 64 * (o & 1);
                int tg = t0 + wm * WMS + mf * 32 + t8 * 8;
                *(uint4*)(vtO + hdbase + (long)dd * Tt + tg) = v;
            }
            __builtin_amdgcn_s_waitcnt(0);
        }
    }
}

__global__ __launch_bounds__(512, 2) void proj_gemm10(
    const unsigned short* __restrict__ xb2,
    const unsigned short* __restrict__ wT2,
    unsigned short* __restrict__ qO,
    unsigned short* __restrict__ kO,
    unsigned short* __restrict__ vtO,
    const float* __restrict__ cosT,
    const float* __restrict__ sinT) {
    __shared__ __align__(16) char lds[131072];
    const int bm = blockIdx.x;          // 0..15 (256 rows each)
    const int bc = blockIdx.y;          // 0..15
    const int s = bc * 384;
    const bool swap = ((s & 2047) == 1920);
    const int offw = swap ? s + 128 : s;
    const int offn = swap ? s : s + 256;
    const int tid = threadIdx.x;

    proj_sub10<true>(xb2, wT2, lds, bm, offw, qO, kO, vtO, cosT, sinT, tid);
    __syncthreads();
    proj_sub10<false>(xb2, wT2, lds, bm, offn, qO, kO, vtO, cosT, sinT, tid);
}

// ---------------------------------------------------------------- flash attention (swapped QK^T, 32x32x16)
__global__ __launch_bounds__(256) void attn_kernel(
    const unsigned short* __restrict__ q,
    const unsigned short* __restrict__ k,
    const unsigned short* __restrict__ vt,
    unsigned short* __restrict__ o) {
    __shared__ __align__(16) unsigned short lds[32768];

    const int lid = (int)blockIdx.x;
    const int p = lid & 255;
    const int bh = p & 31;
    const int q0 = p >> 5;
    const int qb = (lid >> 8) ? (15 - q0) : q0;

    const int tid = threadIdx.x, lane = tid & 63, wave = tid >> 6;
    const int h = lane >> 5, iln = lane & 31;

    const unsigned short* qp = q + (long)bh * Tt * Dd;
    const unsigned short* kp = k + (long)bh * Tt * Dd;
    const unsigned short* vp = vt + (long)bh * Dd * Tt;

    const int i_g = qb * 128 + wave * 32 + iln;
    bf16x8 qf[8];
#pragma unroll
    for (int kk = 0; kk < 8; ++kk)
        qf[kk] = *(const bf16x8*)(qp + (long)i_g * Dd + kk * 16 + h * 8);

    f32x16 accO[4];
#pragma unroll
    for (int nb = 0; nb < 4; ++nb)
#pragma unroll
        for (int e = 0; e < 16; ++e) accO[nb][e] = 0.f;

    float m_r = -1e30f, l_r = 0.f;
    const int ntiles = 2 * qb + 2;

    auto stage = [&](int buf, int tix) {
        const int j0s = tix * 64;
#pragma unroll
        for (int it = 0; it < 4; ++it) {
            int f = it * 256 + tid;
            int rk = f >> 4, ck = f & 15;
            gld16(kp + ((long)(j0s + rk) * Dd + ((ck ^ (rk & 7)) << 3)),
                  (char*)lds + buf * 16384 + f * 16);
            int rv = f >> 3, cv = f & 7;
            gld16(vp + ((long)rv * Tt + j0s + ((cv ^ (rv & 7)) << 3)),
                  (char*)lds + 32768 + buf * 16384 + f * 16);
        }
    };

    stage(0, 0);

    for (int tix = 0; tix < ntiles; ++tix) {
        const int cur = tix & 1;
        const int j0 = tix * 64;
        if (tix + 1 < ntiles) {
            stage(cur ^ 1, tix + 1);
            asm volatile("s_waitcnt vmcnt(8)" ::: "memory");
        } else {
            asm volatile("s_waitcnt vmcnt(0)" ::: "memory");
        }
        __builtin_amdgcn_s_barrier();

        const char* Kb = (const char*)lds + cur * 16384;
        const char* Vb = (const char*)lds + 32768 + cur * 16384;

        f32x16 sacc[2];
#pragma unroll
        for (int mb = 0; mb < 2; ++mb)
#pragma unroll
            for (int e = 0; e < 16; ++e) sacc[mb][e] = 0.f;

        __builtin_amdgcn_s_setprio(1);
#pragma unroll
        for (int mb = 0; mb < 2; ++mb) {
            int row = mb * 32 + iln;
            const char* Kr = Kb + row * 256;
            int sw = row & 7;
#pragma unroll
            for (int kk = 0; kk < 8; ++kk) {
                bf16x8 kf = *(const bf16x8*)(Kr + 16 * ((kk * 2 + h) ^ sw));
                sacc[mb] = __builtin_amdgcn_mfma_f32_32x32x16_bf16(kf, qf[kk], sacc[mb], 0, 0, 0);
            }
        }
        __builtin_amdgcn_s_setprio(0);

        const bool domask = (j0 + 63 > qb * 128);
        if (domask) {
#pragma unroll
            for (int mb = 0; mb < 2; ++mb)
#pragma unroll
                for (int reg = 0; reg < 16; ++reg) {
                    int j = j0 + mb * 32 + (reg & 3) + 8 * (reg >> 2) + 4 * h;
                    if (j > i_g) sacc[mb][reg] = -1e30f;
                }
        }

        float red[16];
#pragma unroll
        for (int r = 0; r < 16; ++r) red[r] = fmaxf(sacc[0][r], sacc[1][r]);
#pragma unroll
        for (int s = 8; s >= 1; s >>= 1)
#pragma unroll
            for (int r = 0; r < s; ++r) red[r] = fmaxf(red[r], red[r + s]);
        float mx = fmaxf(red[0], __shfl_xor(red[0], 32, 64));

        if (__any(mx > m_r + 8.f)) {
            float mn = fmaxf(m_r, mx);
            float corr = fexp2(m_r - mn);
            m_r = mn;
            l_r *= corr;
#pragma unroll
            for (int reg = 0; reg < 16; ++reg) {
                int rrow = (reg & 3) + 8 * (reg >> 2) + 4 * h;
                float c = __shfl(corr, rrow, 64);
#pragma unroll
                for (int nb = 0; nb < 4; ++nb) accO[nb][reg] *= c;
            }
        }

        float pe[2][16];
#pragma unroll
        for (int mb = 0; mb < 2; ++mb)
#pragma unroll
            for (int r = 0; r < 16; ++r) pe[mb][r] = fexp2(sacc[mb][r] - m_r);
        float sr[16];
#pragma unroll
        for (int r = 0; r < 16; ++r) sr[r] = pe[0][r] + pe[1][r];
#pragma unroll
        for (int s = 8; s >= 1; s >>= 1)
#pragma unroll
            for (int r = 0; r < s; ++r) sr[r] += sr[r + s];
        l_r += sr[0] + __shfl_xor(sr[0], 32, 64);

        unsigned int pu[2][8];
#pragma unroll
        for (int mb = 0; mb < 2; ++mb)
#pragma unroll
            for (int t = 0; t < 8; ++t)
                pu[mb][t] = cvt_pk_bf16(pe[mb][2 * t], pe[mb][2 * t + 1]);

        unsigned int rv2[2][4];
#pragma unroll
        for (int mb = 0; mb < 2; ++mb)
#pragma unroll
            for (int u = 0; u < 4; ++u) {
                unsigned int sv = h ? pu[mb][(u & 1) + 4 * (u >> 1)]
                                    : pu[mb][2 + (u & 1) + 4 * (u >> 1)];
                rv2[mb][u] = __shfl_xor(sv, 32, 64);
            }

        __builtin_amdgcn_s_setprio(1);
#pragma unroll
        for (int kk2 = 0; kk2 < 4; ++kk2) {
            const int mb = kk2 >> 1, c2 = kk2 & 1;
            unsigned int w0 = h ? rv2[mb][2 * c2 + 0] : pu[mb][4 * c2 + 0];
            unsigned int w1 = h ? rv2[mb][2 * c2 + 1] : pu[mb][4 * c2 + 1];
            unsigned int w2 = h ? pu[mb][4 * c2 + 2] : rv2[mb][2 * c2 + 0];
            unsigned int w3 = h ? pu[mb][4 * c2 + 3] : rv2[mb][2 * c2 + 1];
            uint4 aw; aw.x = w0; aw.y = w1; aw.z = w2; aw.w = w3;
            bf16x8 af = __builtin_bit_cast(bf16x8, aw);
#pragma unroll
            for (int nb = 0; nb < 4; ++nb) {
                int dd = nb * 32 + iln;
                int byte = dd * 128 + 16 * ((kk2 * 2 + h) ^ (dd & 7));
                bf16x8 vf = *(const bf16x8*)(Vb + byte);
                accO[nb] = __builtin_amdgcn_mfma_f32_32x32x16_bf16(af, vf, accO[nb], 0, 0, 0);
            }
        }
        __builtin_amdgcn_s_setprio(0);

        asm volatile("" ::: "memory");
        __builtin_amdgcn_s_barrier();
    }

    const int b = bh >> 4, hh = bh & 15;
    float invl = 1.f / l_r;
#pragma unroll
    for (int reg = 0; reg < 16; ++reg) {
        int rrow = (reg & 3) + 8 * (reg >> 2) + 4 * h;
        float iv = __shfl(invl, rrow, 64);
        int t = qb * 128 + wave * 32 + rrow;
        long base = ((long)(b * Tt + t) * Hh + hh) * Dd;
#pragma unroll
        for (int nb = 0; nb < 4; ++nb)
            o[base + nb * 32 + iln] = f2bf(accO[nb][reg] * iv);
    }
}

// ---------------------------------------------------------------- output projection GEMM
__global__ __launch_bounds__(256) void out_gemm(
    const unsigned short* __restrict__ oIn,
    const unsigned short* __restrict__ woT,
    float* __restrict__ out) {
    __shared__ __align__(16) unsigned short smem[32768];
    const int bm = blockIdx.x, bn = blockIdx.y;
    const int tid = threadIdx.x;
    const int lane = tid & 63;
    const int wave = tid >> 6;
    const int g = lane >> 4;
    const int ln = lane & 15;

    const unsigned short* arow = oIn + (long)bm * 128 * Mm;
    const unsigned short* brow = woT + (long)bn * 128 * Mm;

    f32x4 acc[2][8];
#pragma unroll
    for (int a = 0; a < 2; ++a)
#pragma unroll
        for (int b2 = 0; b2 < 8; ++b2)
#pragma unroll
            for (int e = 0; e < 4; ++e) acc[a][b2][e] = 0.f;

    auto stage = [&](int buf, int kt) {
        const int k0 = kt * 64;
#pragma unroll
        for (int it = 0; it < 4; ++it) {
            int f = it * 256 + tid;
            int r = f >> 3, c = f & 7;
            long off = (long)r * Mm + k0 + ((c ^ (r & 7)) << 3);
            gld16(arow + off, (char*)smem + buf * 32768 + f * 16);
            gld16(brow + off, (char*)smem + buf * 32768 + 16384 + f * 16);
        }
    };

    stage(0, 0);

    for (int kt = 0; kt < Mm / 64; ++kt) {
        const int cur = kt & 1;
        asm volatile("s_waitcnt vmcnt(0)" ::: "memory");   // stage(kt) landed
        __builtin_amdgcn_s_barrier();
        if (kt + 1 < Mm / 64) stage(cur ^ 1, kt + 1);

        const char* Ab = (const char*)smem + cur * 32768;
        const char* Bv = Ab + 16384;
#pragma unroll
        for (int kc = 0; kc < 2; ++kc) {
            bf16x8 af[2];
#pragma unroll
            for (int rf = 0; rf < 2; ++rf) {
                int row = wave * 32 + rf * 16 + ln;
                int byte = (row * 128 + kc * 64 + g * 16) ^ ((row & 7) << 4);
                af[rf] = *(const bf16x8*)(Ab + byte);
            }
#pragma unroll
            for (int ni = 0; ni < 8; ++ni) {
                int row = ni * 16 + ln;
                int byte = (row * 128 + kc * 64 + g * 16) ^ ((row & 7) << 4);
                bf16x8 bfv = *(const bf16x8*)(Bv + byte);
#pragma unroll
                for (int rf = 0; rf < 2; ++rf)
                    acc[rf][ni] = __builtin_amdgcn_mfma_f32_16x16x32_bf16(af[rf], bfv, acc[rf][ni], 0, 0, 0);
            }
        }
        asm volatile("" ::: "memory");
    }

#pragma unroll
    for (int rf = 0; rf < 2; ++rf)
#pragma unroll
        for (int reg = 0; reg < 4; ++reg) {
            long row = bm * 128 + wave * 32 + rf * 16 + g * 4 + reg;
#pragma unroll
            for (int ni = 0; ni < 8; ++ni)
                out[row * Mm + bn * 128 + ni * 16 + ln] = acc[rf][ni][reg];
        }
}

// ---------------------------------------------------------------- launch

extern "C" void kernel_launch(void* const* d_in, const int* in_sizes, int n_in,
                              void* d_out, int out_size, void* d_ws, size_t ws_size,
                              hipStream_t stream) {
    const float* x    = (const float*)d_in[0];
    const float* w_aq = (const float*)d_in[1];
    const float* w_ak = (const float*)d_in[2];
    const float* w_av = (const float*)d_in[3];
    const float* w_ao = (const float*)d_in[4];
    float* out = (float*)d_out;

    char* ws = (char*)d_ws;
    const long SZ_BTM = 16777216;   // B*T*M * 2B
    const long SZ_W   = 8388608;    // 2048*2048 * 2B
    unsigned short* xb2 = (unsigned short*)(ws);
    unsigned short* qB  = (unsigned short*)(ws + SZ_BTM);
    unsigned short* kB  = (unsigned short*)(ws + 2 * SZ_BTM);
    unsigned short* vtB = (unsigned short*)(ws + 3 * SZ_BTM);
    unsigned short* oB  = (unsigned short*)(ws + 4 * SZ_BTM);
    unsigned short* wT2 = (unsigned short*)(ws + 5 * SZ_BTM);             // 24MB tiled qkv
    unsigned short* woT = (unsigned short*)(ws + 5 * SZ_BTM + 3 * SZ_W);
    float* cosT = (float*)(ws + 5 * SZ_BTM + 4 * SZ_W);
    float* sinT = (float*)(ws + 5 * SZ_BTM + 4 * SZ_W + 524288);

    cvt_x2<<<1024, 256, 0, stream>>>(x, xb2);
    w_qkv_tile<<<dim3(32, 48), 256, 0, stream>>>(w_aq, w_ak, w_av, wT2);
    transpose_cvt<<<dim3(64, 64, 1), 256, 0, stream>>>(w_ao, woT, 2048, 2048, 0, 0);
    rope_tab<<<512, 256, 0, stream>>>(cosT, sinT);

    proj_gemm10<<<dim3(16, 16), 512, 0, stream>>>(xb2, wT2, qB, kB, vtB, cosT, sinT);
    attn_kernel<<<dim3(512), 256, 0, stream>>>(qB, kB, vtB, oB);
    out_gemm<<<dim3(32, 16), 256, 0, stream>>>(oB, woT, out);
}

// Round 16
// 239.014 us; speedup vs baseline: 1.0519x; 1.0127x over previous
//
#include <hip/hip_runtime.h>

#define Bb 2
#define Tt 2048
#define Mm 2048
#define Hh 16
#define Dd 128

typedef __attribute__((ext_vector_type(8))) short bf16x8;
typedef __attribute__((ext_vector_type(4))) float f32x4;
typedef __attribute__((ext_vector_type(16))) float f32x16;

__device__ __forceinline__ unsigned short f2bf(float f) {
    unsigned int u = __builtin_bit_cast(unsigned int, f);
    u += 0x7FFFu + ((u >> 16) & 1u);   // RNE
    return (unsigned short)(u >> 16);
}

__device__ __forceinline__ unsigned int cvt_pk_bf16(float lo, float hi) {
    unsigned int r;
    asm("v_cvt_pk_bf16_f32 %0, %1, %2" : "=v"(r) : "v"(lo), "v"(hi));
    return r;
}

__device__ __forceinline__ float fexp2(float x) { return __builtin_amdgcn_exp2f(x); }

__device__ __forceinline__ void gld16(const void* g, void* l) {
    __builtin_amdgcn_global_load_lds(
        (const __attribute__((address_space(1))) void*)g,
        (__attribute__((address_space(3))) void*)l, 16, 0, 0);
}

// ---------------------------------------------------------------- prep kernels

// x (4096 x 2048 fp32) -> xb2 fragment-tiled bf16
__global__ __launch_bounds__(256) void cvt_x2(const float* __restrict__ x,
                                              unsigned short* __restrict__ xb2) {
    const int blk = blockIdx.x;              // 1024 = 32 mt x 32 kt
    const int mt = blk >> 5, kt = blk & 31;
#pragma unroll
    for (int it = 0; it < 4; ++it) {
        int s = it * 256 + threadIdx.x;
        int row = ((s >> 6) & 3) * 32 + (s & 31);
        int k = (s >> 8) * 16 + ((s >> 5) & 1) * 8;
        const float* sp = x + ((long)(mt * 128 + row)) * 2048 + kt * 64 + k;
        float4 a = *(const float4*)sp;
        float4 b = *(const float4*)(sp + 4);
        uint4 pk;
        pk.x = (unsigned int)f2bf(a.x) | ((unsigned int)f2bf(a.y) << 16);
        pk.y = (unsigned int)f2bf(a.z) | ((unsigned int)f2bf(a.w) << 16);
        pk.z = (unsigned int)f2bf(b.x) | ((unsigned int)f2bf(b.y) << 16);
        pk.w = (unsigned int)f2bf(b.z) | ((unsigned int)f2bf(b.w) << 16);
        *(uint4*)(xb2 + (((long)(mt * 32 + kt)) * 1024 + s) * 8) = pk;
    }
}

// qkv weights -> head-major fragment tiles with RoPE column permutation
__global__ __launch_bounds__(256) void w_qkv_tile(
    const float* __restrict__ wq, const float* __restrict__ wk, const float* __restrict__ wv,
    unsigned short* __restrict__ outBase) {
    __shared__ float tile[64][132];
    const int kt = blockIdx.x;               // 0..31
    const int zy = blockIdx.y;               // 0..47
    const int which = zy >> 4, head = zy & 15;
    const float* src = (which == 0 ? wq : which == 1 ? wk : wv) + (long)head * 2048 * 128;
    const int tid = threadIdx.x;
#pragma unroll
    for (int it = 0; it < 8; ++it) {
        int f = it * 256 + tid;              // 2048 float4s = 64 rows x 32
        int row = f >> 5, c4 = f & 31;
        float4 v = *(const float4*)(src + (long)(kt * 64 + row) * 128 + c4 * 4);
        tile[row][c4 * 4 + 0] = v.x;
        tile[row][c4 * 4 + 1] = v.y;
        tile[row][c4 * 4 + 2] = v.z;
        tile[row][c4 * 4 + 3] = v.w;
    }
    __syncthreads();
    unsigned short* outp = outBase + (((long)(which * 16 + head)) * 32 + kt) * 1024 * 8;
#pragma unroll
    for (int it = 0; it < 4; ++it) {
        int up = it * 256 + tid;
        int kk = up >> 8, nf = (up >> 6) & 3, l = up & 63;
        int il = l & 31, hl = l >> 5;
        int d = il + 64 * (nf & 1) + 32 * (nf >> 1);
        int kl = kk * 16 + hl * 8;
        uint4 pk;
        pk.x = (unsigned int)f2bf(tile[kl + 0][d]) | ((unsigned int)f2bf(tile[kl + 1][d]) << 16);
        pk.y = (unsigned int)f2bf(tile[kl + 2][d]) | ((unsigned int)f2bf(tile[kl + 3][d]) << 16);
        pk.z = (unsigned int)f2bf(tile[kl + 4][d]) | ((unsigned int)f2bf(tile[kl + 5][d]) << 16);
        pk.w = (unsigned int)f2bf(tile[kl + 6][d]) | ((unsigned int)f2bf(tile[kl + 7][d]) << 16);
        *(uint4*)(outp + (long)up * 8) = pk;
    }
}

// w_ao (H,D,M fp32, rows k=h*128+d x cols m) -> fragment-tiled bf16 (no permutation):
// per (nt 128-col, kt 64-k): chunk u = kk*256 + nf*64 + l;
// n = nt*128 + nf*32 + (l&31); k = kt*64 + kk*16 + (l>>5)*8 + e
__global__ __launch_bounds__(256) void w_o_tile(const float* __restrict__ wo,
                                                unsigned short* __restrict__ wo2) {
    __shared__ float tile[64][132];
    const int kt = blockIdx.x;               // 0..31
    const int nt = blockIdx.y;               // 0..15
    const int tid = threadIdx.x;
#pragma unroll
    for (int it = 0; it < 8; ++it) {
        int f = it * 256 + tid;              // 64 rows x 32 float4
        int row = f >> 5, c4 = f & 31;
        float4 v = *(const float4*)(wo + (long)(kt * 64 + row) * 2048 + nt * 128 + c4 * 4);
        tile[row][c4 * 4 + 0] = v.x;
        tile[row][c4 * 4 + 1] = v.y;
        tile[row][c4 * 4 + 2] = v.z;
        tile[row][c4 * 4 + 3] = v.w;
    }
    __syncthreads();
    unsigned short* outp = wo2 + (((long)(nt * 32 + kt)) * 1024) * 8;
#pragma unroll
    for (int it = 0; it < 4; ++it) {
        int up = it * 256 + tid;
        int kk = up >> 8, nf = (up >> 6) & 3, l = up & 63;
        int il = l & 31, hl = l >> 5;
        int n = nf * 32 + il;
        int kl = kk * 16 + hl * 8;
        uint4 pk;
        pk.x = (unsigned int)f2bf(tile[kl + 0][n]) | ((unsigned int)f2bf(tile[kl + 1][n]) << 16);
        pk.y = (unsigned int)f2bf(tile[kl + 2][n]) | ((unsigned int)f2bf(tile[kl + 3][n]) << 16);
        pk.z = (unsigned int)f2bf(tile[kl + 4][n]) | ((unsigned int)f2bf(tile[kl + 5][n]) << 16);
        pk.w = (unsigned int)f2bf(tile[kl + 6][n]) | ((unsigned int)f2bf(tile[kl + 7][n]) << 16);
        *(uint4*)(outp + (long)up * 8) = pk;
    }
}

__global__ __launch_bounds__(256) void rope_tab(float* __restrict__ cosT,
                                                float* __restrict__ sinT) {
    int idx = blockIdx.x * 256 + threadIdx.x;   // T*64
    int t = idx >> 6, d = idx & 63;
    float freq = powf(10000.f, -(float)d / 64.f);
    float ang = (float)t * freq;
    sinT[idx] = sinf(ang);
    cosT[idx] = cosf(ang);
}

// ---------------------------------------------------------------- QKV projection GEMM v10 (R15, plateau-best)
template <bool WIDE>
__device__ __forceinline__ void proj_sub10(
    const unsigned short* __restrict__ xb2,
    const unsigned short* __restrict__ wT2,
    char* lds, int bm, int offc,
    unsigned short* __restrict__ qO, unsigned short* __restrict__ kO,
    unsigned short* __restrict__ vtO,
    const float* __restrict__ cosT, const float* __restrict__ sinT, int tid) {
    const int lane = tid & 63, wave = tid >> 6;
    const int il = lane & 31, hl = lane >> 5;
    const int wm = WIDE ? (wave >> 2) : (wave >> 1);
    const int wn = WIDE ? (wave & 3) : (wave & 1);
    const int hseg0 = offc >> 7;
    const int mode = offc >> 11;
    constexpr int MF = WIDE ? 4 : 2;

    f32x16 acc[MF][2];
#pragma unroll
    for (int a = 0; a < MF; ++a)
#pragma unroll
        for (int b2 = 0; b2 < 2; ++b2)
#pragma unroll
            for (int e = 0; e < 16; ++e) acc[a][b2][e] = 0.f;

    auto stageTo = [&](int buf, int kt) {
        char* dst = lds + buf * 65536;
#pragma unroll
        for (int i = 0; i < 4; ++i) {
            int f = i * 512 + tid;
            int sub = f >> 10, s = f & 1023;
            gld16(xb2 + (((long)((2 * bm + sub) * 32 + kt)) * 1024 + s) * 8, dst + f * 16);
        }
        if (WIDE) {
#pragma unroll
            for (int i = 0; i < 4; ++i) {
                int g = i * 512 + tid;
                int hs = g >> 10, u = g & 1023;
                gld16(wT2 + (((long)((hseg0 + hs) * 32 + kt)) * 1024 + u) * 8,
                      dst + 32768 + g * 16);
            }
        } else {
#pragma unroll
            for (int i = 0; i < 2; ++i) {
                int g = i * 512 + tid;
                gld16(wT2 + (((long)(hseg0 * 32 + kt)) * 1024 + g) * 8,
                      dst + 32768 + g * 16);
            }
        }
    };

    stageTo(0, 0);

    for (int t = 0; t < 32; ++t) {
        const int cur = t & 1;
        if (t + 1 < 32) {
            stageTo(cur ^ 1, t + 1);
            if (WIDE) asm volatile("s_waitcnt vmcnt(8)" ::: "memory");
            else      asm volatile("s_waitcnt vmcnt(6)" ::: "memory");
        } else {
            asm volatile("s_waitcnt vmcnt(0)" ::: "memory");
        }
        __builtin_amdgcn_s_barrier();

        const char* bc = lds + cur * 65536;
        __builtin_amdgcn_s_setprio(1);
#pragma unroll
        for (int kk = 0; kk < 4; ++kk) {
            bf16x8 af[MF], bf[2];
#pragma unroll
            for (int mf = 0; mf < MF; ++mf) {
                int chunk = WIDE ? (wm * 1024 + kk * 256 + mf * 64 + lane)
                                 : ((wm >> 1) * 1024 + kk * 256 + ((wm & 1) * 2 + mf) * 64 + lane);
                af[mf] = *(const bf16x8*)(bc + chunk * 16);
            }
#pragma unroll
            for (int nf2 = 0; nf2 < 2; ++nf2) {
                int chunk = WIDE ? ((wn >> 1) * 1024 + kk * 256 + ((wn & 1) * 2 + nf2) * 64 + lane)
                                 : (kk * 256 + (wn * 2 + nf2) * 64 + lane);
                bf[nf2] = *(const bf16x8*)(bc + 32768 + chunk * 16);
            }
#pragma unroll
            for (int mf = 0; mf < MF; ++mf)
#pragma unroll
                for (int nf2 = 0; nf2 < 2; ++nf2)
                    acc[mf][nf2] = __builtin_amdgcn_mfma_f32_32x32x16_bf16(
                        af[mf], bf[nf2], acc[mf][nf2], 0, 0, 0);
        }
        __builtin_amdgcn_s_setprio(0);
        asm volatile("" ::: "memory");
        __builtin_amdgcn_s_barrier();
    }

    const int b = bm >> 3;
    const int t0 = (bm & 7) * 256;
    const int head_g = WIDE ? (hseg0 + (wn >> 1)) : hseg0;
    const int head_l = head_g & 15;
    const int opar = WIDE ? (wn & 1) : wn;
    constexpr int WMS = WIDE ? 128 : 64;

    if (mode < 2) {
        const float qs = (mode == 0) ? 0.011271055f : 1.0f;  // log2(e)/D folded into q
        unsigned short* outp = (mode == 0) ? qO : kO;
        long hb = ((long)(b * Hh + head_l)) * Tt;
        int d_lo = il + 32 * opar;
#pragma unroll
        for (int mf = 0; mf < MF; ++mf)
#pragma unroll
            for (int reg = 0; reg < 16; ++reg) {
                int r = (reg & 3) + 8 * (reg >> 2) + 4 * hl;
                int tt = t0 + wm * WMS + mf * 32 + r;
                float c = cosT[tt * 64 + d_lo], s = sinT[tt * 64 + d_lo];
                float ev = acc[mf][0][reg], od = acc[mf][1][reg];
                long base = (hb + tt) * Dd;
                outp[base + d_lo]      = f2bf((ev * c - od * s) * qs);
                outp[base + d_lo + 64] = f2bf((ev * s + od * c) * qs);
            }
    } else {
        __syncthreads();
        char* patch = lds + wave * 4096;
        long hdbase = ((long)(b * Hh + head_l)) * Dd * Tt;
#pragma unroll
        for (int mf = 0; mf < MF; ++mf) {
#pragma unroll
            for (int nf = 0; nf < 2; ++nf) {
                int dslot = nf * 32 + il;
                int swz = (dslot & 3) << 4;
#pragma unroll
                for (int qg = 0; qg < 4; ++qg) {
                    uint2 w;
                    w.x = cvt_pk_bf16(acc[mf][nf][qg * 4 + 0], acc[mf][nf][qg * 4 + 1]);
                    w.y = cvt_pk_bf16(acc[mf][nf][qg * 4 + 2], acc[mf][nf][qg * 4 + 3]);
                    *(uint2*)(patch + dslot * 64 + ((qg * 16 + hl * 8) ^ swz)) = w;
                }
            }
            __builtin_amdgcn_s_waitcnt(0);
#pragma unroll
            for (int p2 = 0; p2 < 4; ++p2) {
                int dslot = p2 * 16 + (lane >> 2);
                int t8 = lane & 3;
                uint4 v = *(const uint4*)(patch + dslot * 64 + ((t8 * 16) ^ ((dslot & 3) << 4)));
                int o = opar * 2 + (dslot >> 5), il2 = dslot & 31;
                int dd = il2 + 32 * (o >> 1) + 64 * (o & 1);
                int tg = t0 + wm * WMS + mf * 32 + t8 * 8;
                *(uint4*)(vtO + hdbase + (long)dd * Tt + tg) = v;
            }
            __builtin_amdgcn_s_waitcnt(0);
        }
    }
}

__global__ __launch_bounds__(512, 2) void proj_gemm10(
    const unsigned short* __restrict__ xb2,
    const unsigned short* __restrict__ wT2,
    unsigned short* __restrict__ qO,
    unsigned short* __restrict__ kO,
    unsigned short* __restrict__ vtO,
    const float* __restrict__ cosT,
    const float* __restrict__ sinT) {
    __shared__ __align__(16) char lds[131072];
    const int bm = blockIdx.x;
    const int bc = blockIdx.y;
    const int s = bc * 384;
    const bool swap = ((s & 2047) == 1920);
    const int offw = swap ? s + 128 : s;
    const int offn = swap ? s : s + 256;
    const int tid = threadIdx.x;

    proj_sub10<true>(xb2, wT2, lds, bm, offw, qO, kO, vtO, cosT, sinT, tid);
    __syncthreads();
    proj_sub10<false>(xb2, wT2, lds, bm, offn, qO, kO, vtO, cosT, sinT, tid);
}

// ---------------------------------------------------------------- flash attention (swapped QK^T, 32x32x16)
// epilogue now writes O in A-fragment-tiled layout (oB2) for out_gemm2
__global__ __launch_bounds__(256) void attn_kernel(
    const unsigned short* __restrict__ q,
    const unsigned short* __restrict__ k,
    const unsigned short* __restrict__ vt,
    unsigned short* __restrict__ o2) {
    __shared__ __align__(16) unsigned short lds[32768];

    const int lid = (int)blockIdx.x;
    const int p = lid & 255;
    const int bh = p & 31;
    const int q0 = p >> 5;
    const int qb = (lid >> 8) ? (15 - q0) : q0;

    const int tid = threadIdx.x, lane = tid & 63, wave = tid >> 6;
    const int h = lane >> 5, iln = lane & 31;

    const unsigned short* qp = q + (long)bh * Tt * Dd;
    const unsigned short* kp = k + (long)bh * Tt * Dd;
    const unsigned short* vp = vt + (long)bh * Dd * Tt;

    const int i_g = qb * 128 + wave * 32 + iln;
    bf16x8 qf[8];
#pragma unroll
    for (int kk = 0; kk < 8; ++kk)
        qf[kk] = *(const bf16x8*)(qp + (long)i_g * Dd + kk * 16 + h * 8);

    f32x16 accO[4];
#pragma unroll
    for (int nb = 0; nb < 4; ++nb)
#pragma unroll
        for (int e = 0; e < 16; ++e) accO[nb][e] = 0.f;

    float m_r = -1e30f, l_r = 0.f;
    const int ntiles = 2 * qb + 2;

    auto stage = [&](int buf, int tix) {
        const int j0s = tix * 64;
#pragma unroll
        for (int it = 0; it < 4; ++it) {
            int f = it * 256 + tid;
            int rk = f >> 4, ck = f & 15;
            gld16(kp + ((long)(j0s + rk) * Dd + ((ck ^ (rk & 7)) << 3)),
                  (char*)lds + buf * 16384 + f * 16);
            int rv = f >> 3, cv = f & 7;
            gld16(vp + ((long)rv * Tt + j0s + ((cv ^ (rv & 7)) << 3)),
                  (char*)lds + 32768 + buf * 16384 + f * 16);
        }
    };

    stage(0, 0);

    for (int tix = 0; tix < ntiles; ++tix) {
        const int cur = tix & 1;
        const int j0 = tix * 64;
        if (tix + 1 < ntiles) {
            stage(cur ^ 1, tix + 1);
            asm volatile("s_waitcnt vmcnt(8)" ::: "memory");
        } else {
            asm volatile("s_waitcnt vmcnt(0)" ::: "memory");
        }
        __builtin_amdgcn_s_barrier();

        const char* Kb = (const char*)lds + cur * 16384;
        const char* Vb = (const char*)lds + 32768 + cur * 16384;

        f32x16 sacc[2];
#pragma unroll
        for (int mb = 0; mb < 2; ++mb)
#pragma unroll
            for (int e = 0; e < 16; ++e) sacc[mb][e] = 0.f;

        __builtin_amdgcn_s_setprio(1);
#pragma unroll
        for (int mb = 0; mb < 2; ++mb) {
            int row = mb * 32 + iln;
            const char* Kr = Kb + row * 256;
            int sw = row & 7;
#pragma unroll
            for (int kk = 0; kk < 8; ++kk) {
                bf16x8 kf = *(const bf16x8*)(Kr + 16 * ((kk * 2 + h) ^ sw));
                sacc[mb] = __builtin_amdgcn_mfma_f32_32x32x16_bf16(kf, qf[kk], sacc[mb], 0, 0, 0);
            }
        }
        __builtin_amdgcn_s_setprio(0);

        const bool domask = (j0 + 63 > qb * 128);
        if (domask) {
#pragma unroll
            for (int mb = 0; mb < 2; ++mb)
#pragma unroll
                for (int reg = 0; reg < 16; ++reg) {
                    int j = j0 + mb * 32 + (reg & 3) + 8 * (reg >> 2) + 4 * h;
                    if (j > i_g) sacc[mb][reg] = -1e30f;
                }
        }

        float red[16];
#pragma unroll
        for (int r = 0; r < 16; ++r) red[r] = fmaxf(sacc[0][r], sacc[1][r]);
#pragma unroll
        for (int s = 8; s >= 1; s >>= 1)
#pragma unroll
            for (int r = 0; r < s; ++r) red[r] = fmaxf(red[r], red[r + s]);
        float mx = fmaxf(red[0], __shfl_xor(red[0], 32, 64));

        if (__any(mx > m_r + 8.f)) {
            float mn = fmaxf(m_r, mx);
            float corr = fexp2(m_r - mn);
            m_r = mn;
            l_r *= corr;
#pragma unroll
            for (int reg = 0; reg < 16; ++reg) {
                int rrow = (reg & 3) + 8 * (reg >> 2) + 4 * h;
                float c = __shfl(corr, rrow, 64);
#pragma unroll
                for (int nb = 0; nb < 4; ++nb) accO[nb][reg] *= c;
            }
        }

        float pe[2][16];
#pragma unroll
        for (int mb = 0; mb < 2; ++mb)
#pragma unroll
            for (int r = 0; r < 16; ++r) pe[mb][r] = fexp2(sacc[mb][r] - m_r);
        float sr[16];
#pragma unroll
        for (int r = 0; r < 16; ++r) sr[r] = pe[0][r] + pe[1][r];
#pragma unroll
        for (int s = 8; s >= 1; s >>= 1)
#pragma unroll
            for (int r = 0; r < s; ++r) sr[r] += sr[r + s];
        l_r += sr[0] + __shfl_xor(sr[0], 32, 64);

        unsigned int pu[2][8];
#pragma unroll
        for (int mb = 0; mb < 2; ++mb)
#pragma unroll
            for (int t = 0; t < 8; ++t)
                pu[mb][t] = cvt_pk_bf16(pe[mb][2 * t], pe[mb][2 * t + 1]);

        unsigned int rv2[2][4];
#pragma unroll
        for (int mb = 0; mb < 2; ++mb)
#pragma unroll
            for (int u = 0; u < 4; ++u) {
                unsigned int sv = h ? pu[mb][(u & 1) + 4 * (u >> 1)]
                                    : pu[mb][2 + (u & 1) + 4 * (u >> 1)];
                rv2[mb][u] = __shfl_xor(sv, 32, 64);
            }

        __builtin_amdgcn_s_setprio(1);
#pragma unroll
        for (int kk2 = 0; kk2 < 4; ++kk2) {
            const int mb = kk2 >> 1, c2 = kk2 & 1;
            unsigned int w0 = h ? rv2[mb][2 * c2 + 0] : pu[mb][4 * c2 + 0];
            unsigned int w1 = h ? rv2[mb][2 * c2 + 1] : pu[mb][4 * c2 + 1];
            unsigned int w2 = h ? pu[mb][4 * c2 + 2] : rv2[mb][2 * c2 + 0];
            unsigned int w3 = h ? pu[mb][4 * c2 + 3] : rv2[mb][2 * c2 + 1];
            uint4 aw; aw.x = w0; aw.y = w1; aw.z = w2; aw.w = w3;
            bf16x8 af = __builtin_bit_cast(bf16x8, aw);
#pragma unroll
            for (int nb = 0; nb < 4; ++nb) {
                int dd = nb * 32 + iln;
                int byte = dd * 128 + 16 * ((kk2 * 2 + h) ^ (dd & 7));
                bf16x8 vf = *(const bf16x8*)(Vb + byte);
                accO[nb] = __builtin_amdgcn_mfma_f32_32x32x16_bf16(af, vf, accO[nb], 0, 0, 0);
            }
        }
        __builtin_amdgcn_s_setprio(0);

        asm volatile("" ::: "memory");
        __builtin_amdgcn_s_barrier();
    }

    // epilogue: fragment-tiled O write via per-wave LDS pack
    // oB2 per (mt=rT>>7, kt=k>>6): chunk s = kk4*256 + rb*64 + (rT&31) + 32*hl, elem e
    // here: rb = wave, rT&31 = rrow, kt = hh*2 + (d>>6)
    const int b = bh >> 4, hh = bh & 15;
    float invl = 1.f / l_r;
    char* patch = (char*)lds + wave * 8192;
#pragma unroll
    for (int nb = 0; nb < 4; ++nb)
#pragma unroll
        for (int reg = 0; reg < 16; ++reg) {
            int rrow = (reg & 3) + 8 * (reg >> 2) + 4 * h;
            float iv = __shfl(invl, rrow, 64);
            int d = nb * 32 + iln;
            int byte = (d >> 6) * 4096 + ((d >> 4) & 3) * 1024 +
                       (rrow + 32 * ((d >> 3) & 1)) * 16 + (d & 7) * 2;
            *(unsigned short*)(patch + byte) = f2bf(accO[nb][reg] * iv);
        }
    asm volatile("s_waitcnt lgkmcnt(0)" ::: "memory");
    const int mt = b * 16 + qb;
#pragma unroll
    for (int i = 0; i < 8; ++i) {
        int c = i * 64 + lane;
        int dh = c >> 8, kk4 = (c >> 6) & 3, slot = c & 63;
        uint4 v = *(const uint4*)(patch + c * 16);
        *(uint4*)(o2 + (((long)(mt * 32 + hh * 2 + dh)) * 1024 + kk4 * 256 + wave * 64 + slot) * 8) = v;
    }
}

// ---------------------------------------------------------------- output projection GEMM v2
// 128x256 tile, 8 waves (2M x 4N), per-wave 64x64, 32x32x16, BK=64, dbuf 2x48KB,
// counted vmcnt(6), fragment-major conflict-free LDS, grid (32,8)=256 exact fill.
__global__ __launch_bounds__(512, 2) void out_gemm2(
    const unsigned short* __restrict__ oB2,
    const unsigned short* __restrict__ wo2,
    float* __restrict__ out) {
    __shared__ __align__(16) char lds[98304];
    const int bm = blockIdx.x;   // 0..31 over M=4096
    const int bn = blockIdx.y;   // 0..7  over N=2048
    const int tid = threadIdx.x, lane = tid & 63, wave = tid >> 6;
    const int il = lane & 31, hl = lane >> 5;
    const int wm = wave >> 2, wn = wave & 3;

    f32x16 acc[2][2];
#pragma unroll
    for (int a = 0; a < 2; ++a)
#pragma unroll
        for (int b2 = 0; b2 < 2; ++b2)
#pragma unroll
            for (int e = 0; e < 16; ++e) acc[a][b2][e] = 0.f;

    auto stageTo = [&](int buf, int kt) {
        char* dst = lds + buf * 49152;
#pragma unroll
        for (int i = 0; i < 2; ++i) {
            int f = i * 512 + tid;
            gld16(oB2 + (((long)(bm * 32 + kt)) * 1024 + f) * 8, dst + f * 16);
        }
#pragma unroll
        for (int i = 0; i < 4; ++i) {
            int g = i * 512 + tid;
            int sub = g >> 10, u = g & 1023;
            gld16(wo2 + (((long)((bn * 2 + sub) * 32 + kt)) * 1024 + u) * 8,
                  dst + 16384 + g * 16);
        }
    };

    stageTo(0, 0);

    for (int t = 0; t < 32; ++t) {
        const int cur = t & 1;
        if (t + 1 < 32) {
            stageTo(cur ^ 1, t + 1);
            asm volatile("s_waitcnt vmcnt(6)" ::: "memory");
        } else {
            asm volatile("s_waitcnt vmcnt(0)" ::: "memory");
        }
        __builtin_amdgcn_s_barrier();

        const char* bc = lds + cur * 49152;
        __builtin_amdgcn_s_setprio(1);
#pragma unroll
        for (int kk = 0; kk < 4; ++kk) {
            bf16x8 af[2], bf[2];
#pragma unroll
            for (int mf = 0; mf < 2; ++mf)
                af[mf] = *(const bf16x8*)(bc + (kk * 256 + (wm * 2 + mf) * 64 + lane) * 16);
#pragma unroll
            for (int nf = 0; nf < 2; ++nf)
                bf[nf] = *(const bf16x8*)(bc + 16384 + (wn >> 1) * 16384 +
                                          (kk * 256 + ((wn & 1) * 2 + nf) * 64 + lane) * 16);
#pragma unroll
            for (int mf = 0; mf < 2; ++mf)
#pragma unroll
                for (int nf = 0; nf < 2; ++nf)
                    acc[mf][nf] = __builtin_amdgcn_mfma_f32_32x32x16_bf16(
                        af[mf], bf[nf], acc[mf][nf], 0, 0, 0);
        }
        __builtin_amdgcn_s_setprio(0);
        asm volatile("" ::: "memory");
        __builtin_amdgcn_s_barrier();
    }

#pragma unroll
    for (int mf = 0; mf < 2; ++mf)
#pragma unroll
        for (int nf = 0; nf < 2; ++nf)
#pragma unroll
            for (int reg = 0; reg < 16; ++reg) {
                int r = (reg & 3) + 8 * (reg >> 2) + 4 * hl;
                long row = bm * 128 + wm * 64 + mf * 32 + r;
                int col = bn * 256 + (wn >> 1) * 128 + ((wn & 1) * 2 + nf) * 32 + il;
                out[row * Mm + col] = acc[mf][nf][reg];
            }
}

// ---------------------------------------------------------------- launch

extern "C" void kernel_launch(void* const* d_in, const int* in_sizes, int n_in,
                              void* d_out, int out_size, void* d_ws, size_t ws_size,
                              hipStream_t stream) {
    const float* x    = (const float*)d_in[0];
    const float* w_aq = (const float*)d_in[1];
    const float* w_ak = (const float*)d_in[2];
    const float* w_av = (const float*)d_in[3];
    const float* w_ao = (const float*)d_in[4];
    float* out = (float*)d_out;

    char* ws = (char*)d_ws;
    const long SZ_BTM = 16777216;   // B*T*M * 2B
    const long SZ_W   = 8388608;    // 2048*2048 * 2B
    unsigned short* xb2 = (unsigned short*)(ws);
    unsigned short* qB  = (unsigned short*)(ws + SZ_BTM);
    unsigned short* kB  = (unsigned short*)(ws + 2 * SZ_BTM);
    unsigned short* vtB = (unsigned short*)(ws + 3 * SZ_BTM);
    unsigned short* oB2 = (unsigned short*)(ws + 4 * SZ_BTM);
    unsigned short* wT2 = (unsigned short*)(ws + 5 * SZ_BTM);             // 24MB tiled qkv
    unsigned short* wo2 = (unsigned short*)(ws + 5 * SZ_BTM + 3 * SZ_W);
    float* cosT = (float*)(ws + 5 * SZ_BTM + 4 * SZ_W);
    float* sinT = (float*)(ws + 5 * SZ_BTM + 4 * SZ_W + 524288);

    cvt_x2<<<1024, 256, 0, stream>>>(x, xb2);
    w_qkv_tile<<<dim3(32, 48), 256, 0, stream>>>(w_aq, w_ak, w_av, wT2);
    w_o_tile<<<dim3(32, 16), 256, 0, stream>>>(w_ao, wo2);
    rope_tab<<<512, 256, 0, stream>>>(cosT, sinT);

    proj_gemm10<<<dim3(16, 16), 512, 0, stream>>>(xb2, wT2, qB, kB, vtB, cosT, sinT);
    attn_kernel<<<dim3(512), 256, 0, stream>>>(qB, kB, vtB, oB2);
    out_gemm2<<<dim3(32, 8), 512, 0, stream>>>(oB2, wo2, out);
}